// Round 9
// baseline (176.838 us; speedup 1.0000x reference)
//
#include <hip/hip_runtime.h>

// ---------------------------------------------------------------------------
// MHLP predictor — fused f16 MFMA, instruction-count round.
// R8 post-mortem (88.5 us): VALU 65% + MFMA 14% = ~80% issue-bound; occupancy
// pinned ~37% by total reg alloc (arch VGPR 64 + hidden acc regs -> 4 w/SIMD)
// regardless of LDS. Lever = fewer instructions, not more waves.
//   * one-hot via 3x u32 bitmask (~90 ops vs ~250 compare-chain).
//   * attention WITHOUT cross-lane reduce: token0 qkv depends only on
//     hw_idx (4 variants) -> k_pre precomputes Q0b(q0+bq), K0, V0R(raw v0),
//     V0B(v0+bv), BQ tables (f16). k_fused S3 computes only arch-token
//     q1/k1/v1 (24 MFMA, was 48), writes f16 -> LDS [16][72] x3; S4: each
//     lane owns (sample=l15, head=quad), reads 16 contiguous feats
//     (6x ds_read_b128), scores = in-thread fdot2 dots (0 shuffles; was 128
//     swizzles + 256 adds). d0=(q0+bq)·dk from table; d1=q1·dk+bq·dk;
//     bk cancels in dk; bv cancels in dv. ctx math f32, 4x b128 writes.
// LDS/wave: S1 h[16][136]@0 -> arch[16][72]@0 -> Q1@0,K1@1152,V1@2304
//   -> ctx[32][72]@0 (reads precede writes in-wave) -> pool@0. PWS=3456 u16,
//   block 27648 B (>=4 blk/CU, above the ~4 w/SIMD reg cap).
// Predict: k_fused 88.5 -> ~68-75 us; BANK_CONFLICT 786K -> <450K;
// absmax up to ~3e-3 (f16 qk dots; R3 precedent 3.17e-3 passed).
// ---------------------------------------------------------------------------

using s8v = __attribute__((ext_vector_type(8))) short;
using h8  = __attribute__((ext_vector_type(8))) _Float16;
using h2v = __attribute__((ext_vector_type(2))) _Float16;
using f4  = __attribute__((ext_vector_type(4))) float;

// d_ws u16-unit layout (pre-swizzled f16 weight frags + tables)
#define WF_W1   0        // 12288  (K=75(+bias row 75)->KS=3, NT=8)
#define WF_W2   12288    // 8192   (K=128->KS=4, NT=4)
#define WF_IP   20480    // 12288  (K=64->KS=2, NT=12)
#define WF_OP   32768    // 4096   (K=64->KS=2, NT=4)
#define WF_W3   36864    // 2048   (K=64->KS=2, NT=2)
#define WF_HWE  38912    // 256    (hw_embed f16 [4][64])
#define TQ0     39168    // 256    (q0+bq per hw, f16 [4][64])
#define TK0     39424    // 256    (raw k0)
#define TV0B    39680    // 256    (v0+bv)
#define TV0R    39936    // 256    (raw v0)
#define TBQ     40192    // 64     (q bias f16)

// per-wave LDS: single overlaid region
#define PWS     3456     // u16; 6912 B per wave

__device__ __forceinline__ unsigned short f2h(float f) {
  _Float16 h = (_Float16)f;
  return __builtin_bit_cast(unsigned short, h);
}

__device__ __forceinline__ float dot8(h8 a, h8 b, float acc) {
  const f4 af = __builtin_bit_cast(f4, a), bf = __builtin_bit_cast(f4, b);
#pragma unroll
  for (int u = 0; u < 4; ++u)
    acc = __builtin_amdgcn_fdot2(__builtin_bit_cast(h2v, af[u]),
                                 __builtin_bit_cast(h2v, bf[u]), acc, false);
  return acc;
}

// swizzle W[N][Kreal] row-major f32 -> B-frag f16 layout; optional bias row
// at k == Kreal (folded-bias trick).
__device__ __forceinline__ void swz(const float* __restrict__ W,
                                    const float* __restrict__ bias,
                                    unsigned short* __restrict__ dst,
                                    int Kreal, int KS, int NT, int t, int stride) {
  const int total = KS * NT * 512;
  for (int i = t; i < total; i += stride) {
    const int j = i & 7, ln = (i >> 3) & 63, fr = i >> 9;
    const int nt = fr % NT, ks = fr / NT;
    const int n = nt * 16 + (ln & 15);
    const int k = ks * 32 + (ln >> 4) * 8 + j;
    float v = 0.f;
    if (k < Kreal) v = W[n * Kreal + k];
    else if (bias && k == Kreal) v = bias[n];
    dst[i] = f2h(v);
  }
}

__global__ void k_pre(const float* __restrict__ hwe,
                      const float* __restrict__ W1, const float* __restrict__ b1,
                      const float* __restrict__ W2,
                      const float* __restrict__ ipw, const float* __restrict__ ipb,
                      const float* __restrict__ opw,
                      const float* __restrict__ W3,
                      unsigned short* __restrict__ ws) {
  const int t = blockIdx.x * 256 + threadIdx.x;
  const int stride = gridDim.x * 256;
  swz(W1,  b1,      ws + WF_W1, 75, 3, 8, t, stride);
  swz(W2,  nullptr, ws + WF_W2, 128, 4, 4, t, stride);
  swz(ipw, nullptr, ws + WF_IP, 64, 2, 12, t, stride);
  swz(opw, nullptr, ws + WF_OP, 64, 2, 4, t, stride);
  swz(W3,  nullptr, ws + WF_W3, 64, 2, 2, t, stride);
  for (int i = t; i < 256; i += stride) ws[WF_HWE + i] = f2h(hwe[i]);
  // token-0 qkv tables: qkv0[hw][n] = hw_emb[hw] . in_proj_w[n] (+ bias var.)
  for (int i = t; i < 768; i += stride) {
    const int hw = i / 192, n = i - hw * 192;
    const float* er = hwe + hw * 64;
    const float* wr = ipw + (size_t)n * 64;
    float acc = 0.f;
#pragma unroll 8
    for (int d = 0; d < 64; ++d) acc += er[d] * wr[d];
    if (n < 64)       ws[TQ0  + hw * 64 + n]         = f2h(acc + ipb[n]);
    else if (n < 128) ws[TK0  + hw * 64 + (n - 64)]  = f2h(acc);
    else {            ws[TV0B + hw * 64 + (n - 128)] = f2h(acc + ipb[n]);
                      ws[TV0R + hw * 64 + (n - 128)] = f2h(acc); }
  }
  for (int i = t; i < 64; i += stride) ws[TBQ + i] = f2h(ipb[i]);
}

// ======================= fused: encoder + attention + head =================
__global__ __launch_bounds__(256, 4) void k_fused(
    const int* __restrict__ g_hw,
    const int* __restrict__ g_op, const int* __restrict__ g_wd,
    const float* __restrict__ g_hwe,
    const float* __restrict__ g_b2,
    const float* __restrict__ g_ln1g, const float* __restrict__ g_ln1b,
    const float* __restrict__ g_opb,
    const float* __restrict__ g_ln2g, const float* __restrict__ g_ln2b,
    const float* __restrict__ g_b3,  const float* __restrict__ g_W4,
    const float* __restrict__ g_b4,
    const unsigned short* __restrict__ wsf,   // d_ws base (u16)
    float* __restrict__ g_out) {
  __shared__ __align__(16) unsigned short sm[4 * PWS];
  const int tid = threadIdx.x;
  const int wave = tid >> 6, lane = tid & 63;
  const int quad = lane >> 4, l15 = lane & 15;
  unsigned short* pw = sm + wave * PWS;
  const int m0 = (blockIdx.x * 4 + wave) * 16;   // 4096 blocks x 4 waves

  // ---- index loads (lanes 0..15) + in-wave broadcasts ----
  int hwv = 0, c0 = 0, c1 = 0, c2 = 0, c3 = 0, c4 = 0;
  if (lane < 16) {
    const int smp = m0 + lane;
    hwv = g_hw[smp];
    c0 =      g_op[smp * 5 + 0] * 3 + g_wd[smp * 5 + 0];
    c1 = 15 + g_op[smp * 5 + 1] * 3 + g_wd[smp * 5 + 1];
    c2 = 30 + g_op[smp * 5 + 2] * 3 + g_wd[smp * 5 + 2];
    c3 = 45 + g_op[smp * 5 + 3] * 3 + g_wd[smp * 5 + 3];
    c4 = 60 + g_op[smp * 5 + 4] * 3 + g_wd[smp * 5 + 4];
  }
  const int t0 = __shfl(c0, l15), t1 = __shfl(c1, l15), t2 = __shfl(c2, l15);
  const int t3 = __shfl(c3, l15), t4 = __shfl(c4, l15);
  const int hwrow = __shfl(hwv, l15);

  // ---- hoisted bias/param loads ----
  float b2v[4], l1gv[4], l1bv[4], opbv[4], l2gv[4], l2bv[4];
#pragma unroll
  for (int nt = 0; nt < 4; ++nt) {
    const int col = nt * 16 + l15;
    b2v[nt] = g_b2[col];  l1gv[nt] = g_ln1g[col]; l1bv[nt] = g_ln1b[col];
    opbv[nt] = g_opb[col]; l2gv[nt] = g_ln2g[col]; l2bv[nt] = g_ln2b[col];
  }
  float b3v[2], w4vv[2];
#pragma unroll
  for (int nt = 0; nt < 2; ++nt) {
    b3v[nt] = g_b3[nt * 16 + l15];
    w4vv[nt] = g_W4[nt * 16 + l15];
  }
  const float b4v = g_b4[0];

  // ---- one-hot via 96-bit membership mask (t0,t1 in w0; t3 in w1;
  //      t2 spans w0/w1; t4 spans w1/w2; k=75 bias row in w2 bit 11) ----
  unsigned w0 = (1u << t0) | (1u << t1);
  unsigned w1 = 1u << (t3 - 32);
  unsigned w2 = 1u << 11;
  {
    const unsigned m2 = 1u << (t2 & 31);
    w0 |= (t2 < 32) ? m2 : 0u;
    w1 |= (t2 >= 32) ? m2 : 0u;
    const unsigned m4 = 1u << (t4 & 31);
    w1 |= (t4 < 64) ? m4 : 0u;
    w2 |= (t4 >= 64) ? m4 : 0u;
  }
  h8 aoh[3];
#pragma unroll
  for (int ks = 0; ks < 3; ++ks) {
    const unsigned wm = (ks == 0) ? w0 : (ks == 1) ? w1 : w2;
    const unsigned sh = wm >> (quad * 8);
    s8v a;
#pragma unroll
    for (int j = 0; j < 8; ++j)
      a[j] = ((sh >> j) & 1u) ? (short)0x3C00 : (short)0;
    aoh[ks] = __builtin_bit_cast(h8, a);
  }

  // S1: h = relu(onehot @ [W1;b1]^T) -> pw[0..2176) stride 136 (f16)
#pragma unroll
  for (int nt = 0; nt < 8; ++nt) {
    f4 acc = {0.f, 0.f, 0.f, 0.f};
#pragma unroll
    for (int ks = 0; ks < 3; ++ks) {
      const h8 bf = *(const h8*)(wsf + WF_W1 + ((ks * 8 + nt) * 64 + lane) * 8);
      acc = __builtin_amdgcn_mfma_f32_16x16x32_f16(aoh[ks], bf, acc, 0, 0, 0);
    }
    const int col = nt * 16 + l15;
#pragma unroll
    for (int r = 0; r < 4; ++r) {
      float v = acc[r];
      v = v > 0.f ? v : 0.f;
      pw[(quad * 4 + r) * 136 + col] = f2h(v);
    }
  }

  // S2: arch = LN1(h @ W2^T + b2); arch f16 -> pw@0 stride 72 (h dead after
  // a2 reads), residual f32 in regs.
  h8 a2[4];
#pragma unroll
  for (int ks = 0; ks < 4; ++ks)
    a2[ks] = *(const h8*)(pw + l15 * 136 + ks * 32 + quad * 8);
  float archres[4][4];   // LN1 out f32, layout (row=quad*4+r, col=nt*16+l15)
  {
    float val[4][4];
#pragma unroll
    for (int nt = 0; nt < 4; ++nt) {
      f4 acc = {0.f, 0.f, 0.f, 0.f};
#pragma unroll
      for (int ks = 0; ks < 4; ++ks) {
        const h8 bf = *(const h8*)(wsf + WF_W2 + ((ks * 4 + nt) * 64 + lane) * 8);
        acc = __builtin_amdgcn_mfma_f32_16x16x32_f16(a2[ks], bf, acc, 0, 0, 0);
      }
#pragma unroll
      for (int r = 0; r < 4; ++r) val[nt][r] = acc[r] + b2v[nt];
    }
#pragma unroll
    for (int r = 0; r < 4; ++r) {
      float s = val[0][r] + val[1][r] + val[2][r] + val[3][r];
      float q = val[0][r] * val[0][r] + val[1][r] * val[1][r] +
                val[2][r] * val[2][r] + val[3][r] * val[3][r];
#pragma unroll
      for (int off = 1; off <= 8; off <<= 1) {
        s += __shfl_xor(s, off);
        q += __shfl_xor(q, off);
      }
      const float mean = s * (1.f / 64.f);
      const float var  = q * (1.f / 64.f) - mean * mean;
      const float rstd = rsqrtf(var + 1e-5f);
#pragma unroll
      for (int nt = 0; nt < 4; ++nt) {
        const int col = nt * 16 + l15;
        const float xn = (val[nt][r] - mean) * rstd * l1gv[nt] + l1bv[nt];
        archres[nt][r] = xn;
        pw[(quad * 4 + r) * 72 + col] = f2h(xn);
      }
    }
  }

  // S3 producer: arch-token q1/k1/v1 (no biases) -> LDS f16
  //   Q1 [16][72] @0 (over arch; at1 already in regs), K1 @1152, V1 @2304
  h8 at1[2];
#pragma unroll
  for (int ks = 0; ks < 2; ++ks)
    at1[ks] = *(const h8*)(pw + l15 * 72 + ks * 32 + quad * 8);
#pragma unroll
  for (int h = 0; h < 4; ++h) {
    f4 aq = {0.f,0.f,0.f,0.f}, ak = {0.f,0.f,0.f,0.f}, av = {0.f,0.f,0.f,0.f};
#pragma unroll
    for (int ks = 0; ks < 2; ++ks) {
      const h8 bq = *(const h8*)(wsf + WF_IP + ((ks * 12 + h    ) * 64 + lane) * 8);
      const h8 bk = *(const h8*)(wsf + WF_IP + ((ks * 12 + h + 4) * 64 + lane) * 8);
      const h8 bv = *(const h8*)(wsf + WF_IP + ((ks * 12 + h + 8) * 64 + lane) * 8);
      aq = __builtin_amdgcn_mfma_f32_16x16x32_f16(at1[ks], bq, aq, 0, 0, 0);
      ak = __builtin_amdgcn_mfma_f32_16x16x32_f16(at1[ks], bk, ak, 0, 0, 0);
      av = __builtin_amdgcn_mfma_f32_16x16x32_f16(at1[ks], bv, av, 0, 0, 0);
    }
    const int col = h * 16 + l15;
#pragma unroll
    for (int r = 0; r < 4; ++r) {
      const int row = quad * 4 + r;
      pw[row * 72 + col]        = f2h(aq[r]);
      pw[1152 + row * 72 + col] = f2h(ak[r]);
      pw[2304 + row * 72 + col] = f2h(av[r]);
    }
  }

  // S4 consumer: lane = (sample s=l15, head=quad); in-thread fdot2 scores.
  // All LDS reads precede ctx writes (in-order per wave) -> safe overlay.
  {
    const int qb = quad * 16;
    const unsigned short* q1p = pw + l15 * 72 + qb;
    const h8 q1a = *(const h8*)(q1p),          q1b = *(const h8*)(q1p + 8);
    const h8 k1a = *(const h8*)(q1p + 1152),   k1b = *(const h8*)(q1p + 1160);
    const h8 v1a = *(const h8*)(q1p + 2304),   v1b = *(const h8*)(q1p + 2312);
    const int tb = hwrow * 64 + qb;
    const h8 Q0a = *(const h8*)(wsf + TQ0 + tb),  Q0b = *(const h8*)(wsf + TQ0 + tb + 8);
    const h8 K0a = *(const h8*)(wsf + TK0 + tb),  K0b = *(const h8*)(wsf + TK0 + tb + 8);
    const h8 VBa = *(const h8*)(wsf + TV0B + tb), VBb = *(const h8*)(wsf + TV0B + tb + 8);
    const h8 VRa = *(const h8*)(wsf + TV0R + tb), VRb = *(const h8*)(wsf + TV0R + tb + 8);
    const h8 bqa = *(const h8*)(wsf + TBQ + qb),  bqb = *(const h8*)(wsf + TBQ + qb + 8);
    const h8 dka = k1a - K0a, dkb = k1b - K0b;   // bk cancels
    const float d0 = dot8(Q0a, dka, dot8(Q0b, dkb, 0.f));
    const float d1 = dot8(q1a, dka, dot8(q1b, dkb,
                     dot8(bqa, dka, dot8(bqb, dkb, 0.f))));
    const float a01 = 1.f / (1.f + __expf(-d0 * 0.25f));
    const float a11 = 1.f / (1.f + __expf(-d1 * 0.25f));
    const h8 dva = v1a - VRa, dvb = v1b - VRb;   // bv cancels in dv
    h8 c0a, c0b, c1a, c1b;                       // ctx math in f32
#pragma unroll
    for (int j = 0; j < 8; ++j) {
      const float vb0 = (float)VBa[j], dv0 = (float)dva[j];
      const float vb1 = (float)VBb[j], dv1 = (float)dvb[j];
      c0a[j] = (_Float16)(vb0 + a01 * dv0);
      c0b[j] = (_Float16)(vb1 + a01 * dv1);
      c1a[j] = (_Float16)(vb0 + a11 * dv0);
      c1b[j] = (_Float16)(vb1 + a11 * dv1);
    }
    *(h8*)(pw + l15 * 72 + qb)            = c0a;
    *(h8*)(pw + l15 * 72 + qb + 8)        = c0b;
    *(h8*)(pw + (16 + l15) * 72 + qb)     = c1a;
    *(h8*)(pw + (16 + l15) * 72 + qb + 8) = c1b;
  }

  // S5: out_proj + residual + LN2 + mean-pool -> pool f16 @0 (ctx dead
  // after ca reads)
  h8 ca[2][2];
#pragma unroll
  for (int mt = 0; mt < 2; ++mt)
#pragma unroll
    for (int ks = 0; ks < 2; ++ks)
      ca[mt][ks] = *(const h8*)(pw + (mt * 16 + l15) * 72 + ks * 32 + quad * 8);
  f4 oacc[2][4];
#pragma unroll
  for (int nt = 0; nt < 4; ++nt) {
    const h8 bf0 = *(const h8*)(wsf + WF_OP + ((0 * 4 + nt) * 64 + lane) * 8);
    const h8 bf1 = *(const h8*)(wsf + WF_OP + ((1 * 4 + nt) * 64 + lane) * 8);
#pragma unroll
    for (int mt = 0; mt < 2; ++mt) {
      f4 acc = {0.f, 0.f, 0.f, 0.f};
      acc = __builtin_amdgcn_mfma_f32_16x16x32_f16(ca[mt][0], bf0, acc, 0, 0, 0);
      acc = __builtin_amdgcn_mfma_f32_16x16x32_f16(ca[mt][1], bf1, acc, 0, 0, 0);
      oacc[mt][nt] = acc;
    }
  }
  float pool[4][4];
#pragma unroll
  for (int mt = 0; mt < 2; ++mt) {
    float val[4][4];
#pragma unroll
    for (int r = 0; r < 4; ++r) {
      if (mt == 0) {
        const int hr = __shfl(hwv, quad * 4 + r);
#pragma unroll
        for (int nt = 0; nt < 4; ++nt)
          val[nt][r] = oacc[0][nt][r] + opbv[nt] + g_hwe[hr * 64 + nt * 16 + l15];
      } else {
#pragma unroll
        for (int nt = 0; nt < 4; ++nt)
          val[nt][r] = oacc[1][nt][r] + opbv[nt] + archres[nt][r];
      }
    }
#pragma unroll
    for (int r = 0; r < 4; ++r) {
      float s = val[0][r] + val[1][r] + val[2][r] + val[3][r];
      float q = val[0][r] * val[0][r] + val[1][r] * val[1][r] +
                val[2][r] * val[2][r] + val[3][r] * val[3][r];
#pragma unroll
      for (int off = 1; off <= 8; off <<= 1) {
        s += __shfl_xor(s, off);
        q += __shfl_xor(q, off);
      }
      const float mean = s * (1.f / 64.f);
      const float var  = q * (1.f / 64.f) - mean * mean;
      const float rstd = rsqrtf(var + 1e-5f);
#pragma unroll
      for (int nt = 0; nt < 4; ++nt) {
        const float xn = (val[nt][r] - mean) * rstd * l2gv[nt] + l2bv[nt];
        if (mt == 0) pool[nt][r] = 0.5f * xn;
        else         pool[nt][r] += 0.5f * xn;
      }
    }
  }
#pragma unroll
  for (int nt = 0; nt < 4; ++nt)
#pragma unroll
    for (int r = 0; r < 4; ++r)
      pw[(quad * 4 + r) * 72 + nt * 16 + l15] = f2h(pool[nt][r]);

  // S6: head
  h8 pa[2];
#pragma unroll
  for (int ks = 0; ks < 2; ++ks)
    pa[ks] = *(const h8*)(pw + l15 * 72 + ks * 32 + quad * 8);
  float part[4] = {0.f, 0.f, 0.f, 0.f};
#pragma unroll
  for (int nt = 0; nt < 2; ++nt) {
    const h8 bf0 = *(const h8*)(wsf + WF_W3 + ((0 * 2 + nt) * 64 + lane) * 8);
    const h8 bf1 = *(const h8*)(wsf + WF_W3 + ((1 * 2 + nt) * 64 + lane) * 8);
    f4 acc = {0.f, 0.f, 0.f, 0.f};
    acc = __builtin_amdgcn_mfma_f32_16x16x32_f16(pa[0], bf0, acc, 0, 0, 0);
    acc = __builtin_amdgcn_mfma_f32_16x16x32_f16(pa[1], bf1, acc, 0, 0, 0);
#pragma unroll
    for (int r = 0; r < 4; ++r) {
      float y = acc[r] + b3v[nt];
      y = y > 0.f ? y : 0.f;
      part[r] += y * w4vv[nt];
    }
  }
#pragma unroll
  for (int off = 1; off <= 8; off <<= 1)
#pragma unroll
    for (int r = 0; r < 4; ++r)
      part[r] += __shfl_xor(part[r], off);
  if (l15 == 0) {
#pragma unroll
    for (int r = 0; r < 4; ++r)
      g_out[m0 + quad * 4 + r] = part[r] + b4v;
  }
}

extern "C" void kernel_launch(void* const* d_in, const int* in_sizes, int n_in,
                              void* d_out, int out_size, void* d_ws, size_t ws_size,
                              hipStream_t stream) {
  (void)in_sizes; (void)n_in; (void)out_size; (void)ws_size;
  unsigned short* ws = (unsigned short*)d_ws;

  k_pre<<<64, 256, 0, stream>>>(
      (const float*)d_in[3], (const float*)d_in[4], (const float*)d_in[5],
      (const float*)d_in[6], (const float*)d_in[10], (const float*)d_in[11],
      (const float*)d_in[12], (const float*)d_in[16], ws);

  k_fused<<<4096, 256, 0, stream>>>(
      (const int*)d_in[0],
      (const int*)d_in[1], (const int*)d_in[2],
      (const float*)d_in[3],
      (const float*)d_in[7],
      (const float*)d_in[8], (const float*)d_in[9],
      (const float*)d_in[13],
      (const float*)d_in[14], (const float*)d_in[15],
      (const float*)d_in[17], (const float*)d_in[18],
      (const float*)d_in[19],
      ws, (float*)d_out);
}

// Round 10
// 166.380 us; speedup vs baseline: 1.0629x; 1.0629x over previous
//
#include <hip/hip_runtime.h>

// ---------------------------------------------------------------------------
// MHLP predictor — fused f16 MFMA, memory-level-parallelism round.
// R9 post-mortem (87.7 us, flat): instruction cuts landed (VALU 65->38%,
// VGPR 64->52) but time didn't move -> NOT issue-bound; latency-bound on
// B-frag loads. ~76 b128 loads/wave over a 76 KB frag set > 32 KB L1 ->
// streaming thrash -> every load is an L2 round-trip (~300 cy); VGPR 52
// means ~nothing in flight -> ~23K serial cycles of the ~42K wave lifetime.
// L2 BW only ~14 TB/s << 34.5 -> pure latency. Fix: EXPLICIT LOAD BATCHING
// into register arrays (budget 128 @ lb(256,4), 52 used -> ~70 free):
//   S1: 2 batches of 12 frags; S2: 2x8; S3: 2x12 (2 heads); S5: 1x8; S6: 1x4.
// Batched loads issue together -> MLP 8-12 instead of 1-2. Math unchanged.
// Predict: VGPR ->~100-120, k_fused 87.7 -> ~55-68 us, VALU ~55-65%,
// Mfma ~14-17%, absmax 0.003173828 identical.
// ---------------------------------------------------------------------------

using s8v = __attribute__((ext_vector_type(8))) short;
using h8  = __attribute__((ext_vector_type(8))) _Float16;
using h2v = __attribute__((ext_vector_type(2))) _Float16;
using f4  = __attribute__((ext_vector_type(4))) float;

// d_ws u16-unit layout (pre-swizzled f16 weight frags + tables)
#define WF_W1   0        // 12288  (K=75(+bias row 75)->KS=3, NT=8)
#define WF_W2   12288    // 8192   (K=128->KS=4, NT=4)
#define WF_IP   20480    // 12288  (K=64->KS=2, NT=12)
#define WF_OP   32768    // 4096   (K=64->KS=2, NT=4)
#define WF_W3   36864    // 2048   (K=64->KS=2, NT=2)
#define WF_HWE  38912    // 256    (hw_embed f16 [4][64])
#define TQ0     39168    // 256    (q0+bq per hw, f16 [4][64])
#define TK0     39424    // 256    (raw k0)
#define TV0B    39680    // 256    (v0+bv)
#define TV0R    39936    // 256    (raw v0)
#define TBQ     40192    // 64     (q bias f16)

// per-wave LDS: single overlaid region
#define PWS     3456     // u16; 6912 B per wave

__device__ __forceinline__ unsigned short f2h(float f) {
  _Float16 h = (_Float16)f;
  return __builtin_bit_cast(unsigned short, h);
}

__device__ __forceinline__ float dot8(h8 a, h8 b, float acc) {
  const f4 af = __builtin_bit_cast(f4, a), bf = __builtin_bit_cast(f4, b);
#pragma unroll
  for (int u = 0; u < 4; ++u)
    acc = __builtin_amdgcn_fdot2(__builtin_bit_cast(h2v, af[u]),
                                 __builtin_bit_cast(h2v, bf[u]), acc, false);
  return acc;
}

// swizzle W[N][Kreal] row-major f32 -> B-frag f16 layout; optional bias row
// at k == Kreal (folded-bias trick).
__device__ __forceinline__ void swz(const float* __restrict__ W,
                                    const float* __restrict__ bias,
                                    unsigned short* __restrict__ dst,
                                    int Kreal, int KS, int NT, int t, int stride) {
  const int total = KS * NT * 512;
  for (int i = t; i < total; i += stride) {
    const int j = i & 7, ln = (i >> 3) & 63, fr = i >> 9;
    const int nt = fr % NT, ks = fr / NT;
    const int n = nt * 16 + (ln & 15);
    const int k = ks * 32 + (ln >> 4) * 8 + j;
    float v = 0.f;
    if (k < Kreal) v = W[n * Kreal + k];
    else if (bias && k == Kreal) v = bias[n];
    dst[i] = f2h(v);
  }
}

__global__ void k_pre(const float* __restrict__ hwe,
                      const float* __restrict__ W1, const float* __restrict__ b1,
                      const float* __restrict__ W2,
                      const float* __restrict__ ipw, const float* __restrict__ ipb,
                      const float* __restrict__ opw,
                      const float* __restrict__ W3,
                      unsigned short* __restrict__ ws) {
  const int t = blockIdx.x * 256 + threadIdx.x;
  const int stride = gridDim.x * 256;
  swz(W1,  b1,      ws + WF_W1, 75, 3, 8, t, stride);
  swz(W2,  nullptr, ws + WF_W2, 128, 4, 4, t, stride);
  swz(ipw, nullptr, ws + WF_IP, 64, 2, 12, t, stride);
  swz(opw, nullptr, ws + WF_OP, 64, 2, 4, t, stride);
  swz(W3,  nullptr, ws + WF_W3, 64, 2, 2, t, stride);
  for (int i = t; i < 256; i += stride) ws[WF_HWE + i] = f2h(hwe[i]);
  // token-0 qkv tables: qkv0[hw][n] = hw_emb[hw] . in_proj_w[n] (+ bias var.)
  for (int i = t; i < 768; i += stride) {
    const int hw = i / 192, n = i - hw * 192;
    const float* er = hwe + hw * 64;
    const float* wr = ipw + (size_t)n * 64;
    float acc = 0.f;
#pragma unroll 8
    for (int d = 0; d < 64; ++d) acc += er[d] * wr[d];
    if (n < 64)       ws[TQ0  + hw * 64 + n]         = f2h(acc + ipb[n]);
    else if (n < 128) ws[TK0  + hw * 64 + (n - 64)]  = f2h(acc);
    else {            ws[TV0B + hw * 64 + (n - 128)] = f2h(acc + ipb[n]);
                      ws[TV0R + hw * 64 + (n - 128)] = f2h(acc); }
  }
  for (int i = t; i < 64; i += stride) ws[TBQ + i] = f2h(ipb[i]);
}

// ======================= fused: encoder + attention + head =================
__global__ __launch_bounds__(256, 4) void k_fused(
    const int* __restrict__ g_hw,
    const int* __restrict__ g_op, const int* __restrict__ g_wd,
    const float* __restrict__ g_hwe,
    const float* __restrict__ g_b2,
    const float* __restrict__ g_ln1g, const float* __restrict__ g_ln1b,
    const float* __restrict__ g_opb,
    const float* __restrict__ g_ln2g, const float* __restrict__ g_ln2b,
    const float* __restrict__ g_b3,  const float* __restrict__ g_W4,
    const float* __restrict__ g_b4,
    const unsigned short* __restrict__ wsf,   // d_ws base (u16)
    float* __restrict__ g_out) {
  __shared__ __align__(16) unsigned short sm[4 * PWS];
  const int tid = threadIdx.x;
  const int wave = tid >> 6, lane = tid & 63;
  const int quad = lane >> 4, l15 = lane & 15;
  unsigned short* pw = sm + wave * PWS;
  const int m0 = (blockIdx.x * 4 + wave) * 16;   // 4096 blocks x 4 waves

  // ---- index loads (lanes 0..15) + in-wave broadcasts ----
  int hwv = 0, c0 = 0, c1 = 0, c2 = 0, c3 = 0, c4 = 0;
  if (lane < 16) {
    const int smp = m0 + lane;
    hwv = g_hw[smp];
    c0 =      g_op[smp * 5 + 0] * 3 + g_wd[smp * 5 + 0];
    c1 = 15 + g_op[smp * 5 + 1] * 3 + g_wd[smp * 5 + 1];
    c2 = 30 + g_op[smp * 5 + 2] * 3 + g_wd[smp * 5 + 2];
    c3 = 45 + g_op[smp * 5 + 3] * 3 + g_wd[smp * 5 + 3];
    c4 = 60 + g_op[smp * 5 + 4] * 3 + g_wd[smp * 5 + 4];
  }
  const int t0 = __shfl(c0, l15), t1 = __shfl(c1, l15), t2 = __shfl(c2, l15);
  const int t3 = __shfl(c3, l15), t4 = __shfl(c4, l15);
  const int hwrow = __shfl(hwv, l15);

  // ---- hoisted bias/param loads ----
  float b2v[4], l1gv[4], l1bv[4], opbv[4], l2gv[4], l2bv[4];
#pragma unroll
  for (int nt = 0; nt < 4; ++nt) {
    const int col = nt * 16 + l15;
    b2v[nt] = g_b2[col];  l1gv[nt] = g_ln1g[col]; l1bv[nt] = g_ln1b[col];
    opbv[nt] = g_opb[col]; l2gv[nt] = g_ln2g[col]; l2bv[nt] = g_ln2b[col];
  }
  float b3v[2], w4vv[2];
#pragma unroll
  for (int nt = 0; nt < 2; ++nt) {
    b3v[nt] = g_b3[nt * 16 + l15];
    w4vv[nt] = g_W4[nt * 16 + l15];
  }
  const float b4v = g_b4[0];

  // ---- one-hot via 96-bit membership mask ----
  unsigned w0 = (1u << t0) | (1u << t1);
  unsigned w1 = 1u << (t3 - 32);
  unsigned w2 = 1u << 11;
  {
    const unsigned m2 = 1u << (t2 & 31);
    w0 |= (t2 < 32) ? m2 : 0u;
    w1 |= (t2 >= 32) ? m2 : 0u;
    const unsigned m4 = 1u << (t4 & 31);
    w1 |= (t4 < 64) ? m4 : 0u;
    w2 |= (t4 >= 64) ? m4 : 0u;
  }
  h8 aoh[3];
#pragma unroll
  for (int ks = 0; ks < 3; ++ks) {
    const unsigned wm = (ks == 0) ? w0 : (ks == 1) ? w1 : w2;
    const unsigned sh = wm >> (quad * 8);
    s8v a;
#pragma unroll
    for (int j = 0; j < 8; ++j)
      a[j] = ((sh >> j) & 1u) ? (short)0x3C00 : (short)0;
    aoh[ks] = __builtin_bit_cast(h8, a);
  }

  // S1: h = relu(onehot @ [W1;b1]^T) -> pw[0..2176) stride 136 (f16)
  // Batched: 2 halves x {12 frag loads in flight -> 12 MFMA}
#pragma unroll
  for (int half = 0; half < 2; ++half) {
    h8 bf[12];
#pragma unroll
    for (int n2 = 0; n2 < 4; ++n2)
#pragma unroll
      for (int ks = 0; ks < 3; ++ks)
        bf[n2 * 3 + ks] = *(const h8*)(wsf + WF_W1 +
            ((ks * 8 + half * 4 + n2) * 64 + lane) * 8);
#pragma unroll
    for (int n2 = 0; n2 < 4; ++n2) {
      f4 acc = {0.f, 0.f, 0.f, 0.f};
#pragma unroll
      for (int ks = 0; ks < 3; ++ks)
        acc = __builtin_amdgcn_mfma_f32_16x16x32_f16(aoh[ks], bf[n2 * 3 + ks],
                                                     acc, 0, 0, 0);
      const int col = (half * 4 + n2) * 16 + l15;
#pragma unroll
      for (int r = 0; r < 4; ++r) {
        float v = acc[r];
        v = v > 0.f ? v : 0.f;
        pw[(quad * 4 + r) * 136 + col] = f2h(v);
      }
    }
  }

  // S2: arch = LN1(h @ W2^T + b2); arch f16 -> pw@0 stride 72 (h dead after
  // a2 reads), residual f32 in regs.  Batched: 2 halves x 8 frags.
  h8 a2[4];
#pragma unroll
  for (int ks = 0; ks < 4; ++ks)
    a2[ks] = *(const h8*)(pw + l15 * 136 + ks * 32 + quad * 8);
  float archres[4][4];   // LN1 out f32, layout (row=quad*4+r, col=nt*16+l15)
  {
    float val[4][4];
#pragma unroll
    for (int half = 0; half < 2; ++half) {
      h8 bf[8];
#pragma unroll
      for (int n2 = 0; n2 < 2; ++n2)
#pragma unroll
        for (int ks = 0; ks < 4; ++ks)
          bf[n2 * 4 + ks] = *(const h8*)(wsf + WF_W2 +
              ((ks * 4 + half * 2 + n2) * 64 + lane) * 8);
#pragma unroll
      for (int n2 = 0; n2 < 2; ++n2) {
        f4 acc = {0.f, 0.f, 0.f, 0.f};
#pragma unroll
        for (int ks = 0; ks < 4; ++ks)
          acc = __builtin_amdgcn_mfma_f32_16x16x32_f16(a2[ks], bf[n2 * 4 + ks],
                                                       acc, 0, 0, 0);
        const int nt = half * 2 + n2;
#pragma unroll
        for (int r = 0; r < 4; ++r) val[nt][r] = acc[r] + b2v[nt];
      }
    }
#pragma unroll
    for (int r = 0; r < 4; ++r) {
      float s = val[0][r] + val[1][r] + val[2][r] + val[3][r];
      float q = val[0][r] * val[0][r] + val[1][r] * val[1][r] +
                val[2][r] * val[2][r] + val[3][r] * val[3][r];
#pragma unroll
      for (int off = 1; off <= 8; off <<= 1) {
        s += __shfl_xor(s, off);
        q += __shfl_xor(q, off);
      }
      const float mean = s * (1.f / 64.f);
      const float var  = q * (1.f / 64.f) - mean * mean;
      const float rstd = rsqrtf(var + 1e-5f);
#pragma unroll
      for (int nt = 0; nt < 4; ++nt) {
        const int col = nt * 16 + l15;
        const float xn = (val[nt][r] - mean) * rstd * l1gv[nt] + l1bv[nt];
        archres[nt][r] = xn;
        pw[(quad * 4 + r) * 72 + col] = f2h(xn);
      }
    }
  }

  // S3 producer: arch-token q1/k1/v1 (no biases) -> LDS f16
  //   Q1 [16][72] @0 (over arch; at1 already in regs), K1 @1152, V1 @2304
  // Batched: 2 halves (2 heads each) x 12 frags.
  h8 at1[2];
#pragma unroll
  for (int ks = 0; ks < 2; ++ks)
    at1[ks] = *(const h8*)(pw + l15 * 72 + ks * 32 + quad * 8);
#pragma unroll
  for (int hh = 0; hh < 2; ++hh) {
    h8 bf[12];   // [h2][qkv][ks]
#pragma unroll
    for (int h2 = 0; h2 < 2; ++h2) {
      const int h = hh * 2 + h2;
#pragma unroll
      for (int ks = 0; ks < 2; ++ks) {
        bf[h2 * 6 + 0 + ks] = *(const h8*)(wsf + WF_IP + ((ks * 12 + h    ) * 64 + lane) * 8);
        bf[h2 * 6 + 2 + ks] = *(const h8*)(wsf + WF_IP + ((ks * 12 + h + 4) * 64 + lane) * 8);
        bf[h2 * 6 + 4 + ks] = *(const h8*)(wsf + WF_IP + ((ks * 12 + h + 8) * 64 + lane) * 8);
      }
    }
#pragma unroll
    for (int h2 = 0; h2 < 2; ++h2) {
      const int h = hh * 2 + h2;
      f4 aq = {0.f,0.f,0.f,0.f}, ak = {0.f,0.f,0.f,0.f}, av = {0.f,0.f,0.f,0.f};
#pragma unroll
      for (int ks = 0; ks < 2; ++ks) {
        aq = __builtin_amdgcn_mfma_f32_16x16x32_f16(at1[ks], bf[h2 * 6 + 0 + ks], aq, 0, 0, 0);
        ak = __builtin_amdgcn_mfma_f32_16x16x32_f16(at1[ks], bf[h2 * 6 + 2 + ks], ak, 0, 0, 0);
        av = __builtin_amdgcn_mfma_f32_16x16x32_f16(at1[ks], bf[h2 * 6 + 4 + ks], av, 0, 0, 0);
      }
      const int col = h * 16 + l15;
#pragma unroll
      for (int r = 0; r < 4; ++r) {
        const int row = quad * 4 + r;
        pw[row * 72 + col]        = f2h(aq[r]);
        pw[1152 + row * 72 + col] = f2h(ak[r]);
        pw[2304 + row * 72 + col] = f2h(av[r]);
      }
    }
  }

  // S4 consumer: lane = (sample s=l15, head=quad); in-thread fdot2 scores.
  {
    const int qb = quad * 16;
    const unsigned short* q1p = pw + l15 * 72 + qb;
    const h8 q1a = *(const h8*)(q1p),          q1b = *(const h8*)(q1p + 8);
    const h8 k1a = *(const h8*)(q1p + 1152),   k1b = *(const h8*)(q1p + 1160);
    const h8 v1a = *(const h8*)(q1p + 2304),   v1b = *(const h8*)(q1p + 2312);
    const int tb = hwrow * 64 + qb;
    const h8 Q0a = *(const h8*)(wsf + TQ0 + tb),  Q0b = *(const h8*)(wsf + TQ0 + tb + 8);
    const h8 K0a = *(const h8*)(wsf + TK0 + tb),  K0b = *(const h8*)(wsf + TK0 + tb + 8);
    const h8 VBa = *(const h8*)(wsf + TV0B + tb), VBb = *(const h8*)(wsf + TV0B + tb + 8);
    const h8 VRa = *(const h8*)(wsf + TV0R + tb), VRb = *(const h8*)(wsf + TV0R + tb + 8);
    const h8 bqa = *(const h8*)(wsf + TBQ + qb),  bqb = *(const h8*)(wsf + TBQ + qb + 8);
    const h8 dka = k1a - K0a, dkb = k1b - K0b;   // bk cancels
    const float d0 = dot8(Q0a, dka, dot8(Q0b, dkb, 0.f));
    const float d1 = dot8(q1a, dka, dot8(q1b, dkb,
                     dot8(bqa, dka, dot8(bqb, dkb, 0.f))));
    const float a01 = 1.f / (1.f + __expf(-d0 * 0.25f));
    const float a11 = 1.f / (1.f + __expf(-d1 * 0.25f));
    const h8 dva = v1a - VRa, dvb = v1b - VRb;   // bv cancels in dv
    h8 c0a, c0b, c1a, c1b;                       // ctx math in f32
#pragma unroll
    for (int j = 0; j < 8; ++j) {
      const float vb0 = (float)VBa[j], dv0 = (float)dva[j];
      const float vb1 = (float)VBb[j], dv1 = (float)dvb[j];
      c0a[j] = (_Float16)(vb0 + a01 * dv0);
      c0b[j] = (_Float16)(vb1 + a01 * dv1);
      c1a[j] = (_Float16)(vb0 + a11 * dv0);
      c1b[j] = (_Float16)(vb1 + a11 * dv1);
    }
    *(h8*)(pw + l15 * 72 + qb)            = c0a;
    *(h8*)(pw + l15 * 72 + qb + 8)        = c0b;
    *(h8*)(pw + (16 + l15) * 72 + qb)     = c1a;
    *(h8*)(pw + (16 + l15) * 72 + qb + 8) = c1b;
  }

  // S5: out_proj + residual + LN2 + mean-pool -> pool f16 @0 (ctx dead
  // after ca reads).  Batched: all 8 frags in flight.
  h8 ca[2][2];
#pragma unroll
  for (int mt = 0; mt < 2; ++mt)
#pragma unroll
    for (int ks = 0; ks < 2; ++ks)
      ca[mt][ks] = *(const h8*)(pw + (mt * 16 + l15) * 72 + ks * 32 + quad * 8);
  f4 oacc[2][4];
  {
    h8 bf[8];
#pragma unroll
    for (int nt = 0; nt < 4; ++nt)
#pragma unroll
      for (int ks = 0; ks < 2; ++ks)
        bf[nt * 2 + ks] = *(const h8*)(wsf + WF_OP + ((ks * 4 + nt) * 64 + lane) * 8);
#pragma unroll
    for (int nt = 0; nt < 4; ++nt)
#pragma unroll
      for (int mt = 0; mt < 2; ++mt) {
        f4 acc = {0.f, 0.f, 0.f, 0.f};
        acc = __builtin_amdgcn_mfma_f32_16x16x32_f16(ca[mt][0], bf[nt * 2 + 0], acc, 0, 0, 0);
        acc = __builtin_amdgcn_mfma_f32_16x16x32_f16(ca[mt][1], bf[nt * 2 + 1], acc, 0, 0, 0);
        oacc[mt][nt] = acc;
      }
  }
  float pool[4][4];
#pragma unroll
  for (int mt = 0; mt < 2; ++mt) {
    float val[4][4];
#pragma unroll
    for (int r = 0; r < 4; ++r) {
      if (mt == 0) {
        const int hr = __shfl(hwv, quad * 4 + r);
#pragma unroll
        for (int nt = 0; nt < 4; ++nt)
          val[nt][r] = oacc[0][nt][r] + opbv[nt] + g_hwe[hr * 64 + nt * 16 + l15];
      } else {
#pragma unroll
        for (int nt = 0; nt < 4; ++nt)
          val[nt][r] = oacc[1][nt][r] + opbv[nt] + archres[nt][r];
      }
    }
#pragma unroll
    for (int r = 0; r < 4; ++r) {
      float s = val[0][r] + val[1][r] + val[2][r] + val[3][r];
      float q = val[0][r] * val[0][r] + val[1][r] * val[1][r] +
                val[2][r] * val[2][r] + val[3][r] * val[3][r];
#pragma unroll
      for (int off = 1; off <= 8; off <<= 1) {
        s += __shfl_xor(s, off);
        q += __shfl_xor(q, off);
      }
      const float mean = s * (1.f / 64.f);
      const float var  = q * (1.f / 64.f) - mean * mean;
      const float rstd = rsqrtf(var + 1e-5f);
#pragma unroll
      for (int nt = 0; nt < 4; ++nt) {
        const float xn = (val[nt][r] - mean) * rstd * l2gv[nt] + l2bv[nt];
        if (mt == 0) pool[nt][r] = 0.5f * xn;
        else         pool[nt][r] += 0.5f * xn;
      }
    }
  }
#pragma unroll
  for (int nt = 0; nt < 4; ++nt)
#pragma unroll
    for (int r = 0; r < 4; ++r)
      pw[(quad * 4 + r) * 72 + nt * 16 + l15] = f2h(pool[nt][r]);

  // S6: head (4 frags batched)
  h8 pa[2];
#pragma unroll
  for (int ks = 0; ks < 2; ++ks)
    pa[ks] = *(const h8*)(pw + l15 * 72 + ks * 32 + quad * 8);
  float part[4] = {0.f, 0.f, 0.f, 0.f};
  {
    h8 bf[4];
#pragma unroll
    for (int nt = 0; nt < 2; ++nt)
#pragma unroll
      for (int ks = 0; ks < 2; ++ks)
        bf[nt * 2 + ks] = *(const h8*)(wsf + WF_W3 + ((ks * 2 + nt) * 64 + lane) * 8);
#pragma unroll
    for (int nt = 0; nt < 2; ++nt) {
      f4 acc = {0.f, 0.f, 0.f, 0.f};
      acc = __builtin_amdgcn_mfma_f32_16x16x32_f16(pa[0], bf[nt * 2 + 0], acc, 0, 0, 0);
      acc = __builtin_amdgcn_mfma_f32_16x16x32_f16(pa[1], bf[nt * 2 + 1], acc, 0, 0, 0);
#pragma unroll
      for (int r = 0; r < 4; ++r) {
        float y = acc[r] + b3v[nt];
        y = y > 0.f ? y : 0.f;
        part[r] += y * w4vv[nt];
      }
    }
  }
#pragma unroll
  for (int off = 1; off <= 8; off <<= 1)
#pragma unroll
    for (int r = 0; r < 4; ++r)
      part[r] += __shfl_xor(part[r], off);
  if (l15 == 0) {
#pragma unroll
    for (int r = 0; r < 4; ++r)
      g_out[m0 + quad * 4 + r] = part[r] + b4v;
  }
}

extern "C" void kernel_launch(void* const* d_in, const int* in_sizes, int n_in,
                              void* d_out, int out_size, void* d_ws, size_t ws_size,
                              hipStream_t stream) {
  (void)in_sizes; (void)n_in; (void)out_size; (void)ws_size;
  unsigned short* ws = (unsigned short*)d_ws;

  k_pre<<<64, 256, 0, stream>>>(
      (const float*)d_in[3], (const float*)d_in[4], (const float*)d_in[5],
      (const float*)d_in[6], (const float*)d_in[10], (const float*)d_in[11],
      (const float*)d_in[12], (const float*)d_in[16], ws);

  k_fused<<<4096, 256, 0, stream>>>(
      (const int*)d_in[0],
      (const int*)d_in[1], (const int*)d_in[2],
      (const float*)d_in[3],
      (const float*)d_in[7],
      (const float*)d_in[8], (const float*)d_in[9],
      (const float*)d_in[13],
      (const float*)d_in[14], (const float*)d_in[15],
      (const float*)d_in[17], (const float*)d_in[18],
      (const float*)d_in[19],
      ws, (float*)d_out);
}